// Round 18
// baseline (36.300 us; speedup 1.0000x reference)
//
#include <hip/hip_runtime.h>
#include <math.h>

// DisCo (distance correlation) for N=8192, scalar output. THREE dispatches.
// R18 = R17 with pass1 ALSO at 16 rows/block (512 blocks): halves pass1's L2
// read traffic (100->50 MB), doubles VALU/byte; 2 waves/SIMD covered by 16
// indep FMA chains (ILP-for-TLP, validated by R17's pass2).
// Algebra (validated R11/R13/R15/R16, absmax 0.0):
//   ha = Sua1/(2N) (Sua1 = sum w_i avga_i); r_i = avga_i - ha
//   Q'_i = sum_j w_j (|a_i-a_j| - r_j)(|b_i-b_j| - s_j)   (5 VALU/pair)
//   T_AB_i = Q'_i - s_i(P0a_i-Swr) - r_i(P0b_i-Sws) + r_i s_i W
//   S_AA = 2W*Ma2 - 2Ma1^2 - 4N(Swr2 + ha*Swr) + 2W*Swr2 + 2Swr^2 (closed)
//   K1 k_pass1 (512):  16 full rows/block; avg + 9 ha-free moment partials.
//   K2 k_pass2 (512):  16 full rows/block; prologue scalars; 5-op Q' sweep;
//       in-block T_AB -> fAB[512].
//   K3 k_fin   (1x256): reduce fAB + moments; closed-form dens; power; clamp.
// No atomics/fences (R4). Fixed-order reductions -> deterministic.
// Ledger: R4 no per-block fences; R6 VGPR cliff; R9 epilogue<<main, 1-block
// reads <<100KB; R10 no redundant per-block O(N) rebuilds; R12 serial merge
// loses to gap; R14 packed-f32 neutral; R15/R17/R18 ILP-for-TLP.

#define NN 8192
#define BLK 256
#define NW 4                      // waves per block
#define RP 16                     // rows per block (both passes)
#define GBLK (NN / RP)            // 512 blocks (both passes)
#define SEGC (NN / NW)            // 2048 cols per wave
#define ITERS (SEGC / 256)        // 8 float4-iters per wave
#define NSC 9   // 0:W 1:Ma1 2:Ma2 3:Mb1 4:Mb2 5:Sua1 6:Sua2 7:Sub1 8:Sub2

// ------------------------- K1: pass 1 — 16 full rows, avg + ha-free moments
__global__ __launch_bounds__(BLK) void k_pass1(
    const float* __restrict__ a, const float* __restrict__ b,
    const float* __restrict__ w,
    float* __restrict__ avga, float* __restrict__ avgb,
    double* __restrict__ gmom) {
  const int lane = threadIdx.x & 63;
  const int wv = threadIdx.x >> 6;
  const int i0 = blockIdx.x * RP;

  float ai[RP], bi[RP], sa[RP], sb[RP];
#pragma unroll
  for (int m = 0; m < RP; ++m) {
    ai[m] = a[i0 + m]; bi[m] = b[i0 + m];
    sa[m] = 0.f; sb[m] = 0.f;
  }

  const int jb = wv * SEGC;
  const float4* a4 = (const float4*)(a + jb) + lane;
  const float4* b4 = (const float4*)(b + jb) + lane;
  const float4* w4 = (const float4*)(w + jb) + lane;

#pragma unroll 1
  for (int k = 0; k < ITERS; ++k) {
    const int ix = k * 64;
    const float4 A = a4[ix], B = b4[ix], Wt = w4[ix];
#define P1E(e)                                              \
    {                                                       \
      _Pragma("unroll")                                     \
      for (int m = 0; m < RP; ++m) {                        \
        sa[m] = fmaf(fabsf(ai[m] - A.e), Wt.e, sa[m]);      \
        sb[m] = fmaf(fabsf(bi[m] - B.e), Wt.e, sb[m]);      \
      }                                                     \
    }
    P1E(x) P1E(y) P1E(z) P1E(w)
#undef P1E
  }

#pragma unroll
  for (int off = 32; off >= 1; off >>= 1) {
#pragma unroll
    for (int m = 0; m < RP; ++m) {
      sa[m] += __shfl_xor(sa[m], off);
      sb[m] += __shfl_xor(sb[m], off);
    }
  }

  __shared__ float lsa[NW][RP], lsb[NW][RP];
  __shared__ double dmom[RP][NSC];
  if (lane == 0) {
#pragma unroll
    for (int m = 0; m < RP; ++m) { lsa[wv][m] = sa[m]; lsb[wv][m] = sb[m]; }
  }
  __syncthreads();
  if (threadIdx.x < RP) {
    const int m = threadIdx.x;
    const double rowA = (double)lsa[0][m] + lsa[1][m] + lsa[2][m] + lsa[3][m];
    const double rowB = (double)lsb[0][m] + lsb[1][m] + lsb[2][m] + lsb[3][m];
    const double avA = rowA * (1.0 / NN);
    const double avB = rowB * (1.0 / NN);
    avga[i0 + m] = (float)avA;
    avgb[i0 + m] = (float)avB;
    const double wi = (double)w[i0 + m];
    const double aiv = (double)a[i0 + m];
    const double biv = (double)b[i0 + m];
    dmom[m][0] = wi;
    dmom[m][1] = wi * aiv;
    dmom[m][2] = wi * aiv * aiv;
    dmom[m][3] = wi * biv;
    dmom[m][4] = wi * biv * biv;
    dmom[m][5] = wi * avA;
    dmom[m][6] = wi * avA * avA;
    dmom[m][7] = wi * avB;
    dmom[m][8] = wi * avB * avB;
  }
  __syncthreads();
  if (threadIdx.x == 0) {
#pragma unroll
    for (int t = 0; t < NSC; ++t) {
      double s = 0.0;
#pragma unroll
      for (int m = 0; m < RP; ++m) s += dmom[m][t];
      gmom[t * GBLK + blockIdx.x] = s;
    }
  }
}

// ---- K2: pass 2 — 16 full rows/block; prologue scalars; 5-op Q' sweep;
//      in-block T_AB finish -> fAB[512]
__global__ __launch_bounds__(BLK) void k_pass2(
    const float* __restrict__ a, const float* __restrict__ b,
    const float* __restrict__ w,
    const float* __restrict__ avga, const float* __restrict__ avgb,
    const double* __restrict__ gmom,
    double* __restrict__ fAB) {
  const int lane = threadIdx.x & 63;
  const int wv = threadIdx.x >> 6;
  const int i0 = blockIdx.x * RP;

  // ---- prologue: W, Sua1, Sub1 -> ha, hb, Swr, Sws (all threads)
  double pW = 0.0, pU = 0.0, pV = 0.0;
#pragma unroll
  for (int k = 0; k < GBLK / BLK; ++k) {
    const int t = threadIdx.x + k * BLK;
    pW += gmom[0 * GBLK + t];
    pU += gmom[5 * GBLK + t];
    pV += gmom[7 * GBLK + t];
  }
#pragma unroll
  for (int off = 32; off >= 1; off >>= 1) {
    pW += __shfl_xor(pW, off);
    pU += __shfl_xor(pU, off);
    pV += __shfl_xor(pV, off);
  }
  __shared__ double l3[3][NW];
  if (lane == 0) { l3[0][wv] = pW; l3[1][wv] = pU; l3[2][wv] = pV; }
  __syncthreads();
  const double Wd   = l3[0][0] + l3[0][1] + l3[0][2] + l3[0][3];
  const double Sua1 = l3[1][0] + l3[1][1] + l3[1][2] + l3[1][3];
  const double Sub1 = l3[2][0] + l3[2][1] + l3[2][2] + l3[2][3];
  const double had = Sua1 / (2.0 * NN);
  const double hbd = Sub1 / (2.0 * NN);
  const double Swrd = Sua1 - had * Wd;
  const double Swsd = Sub1 - hbd * Wd;
  const float ha = (float)had, hb = (float)hbd;

  float ai[RP], bi[RP], q[RP];
#pragma unroll
  for (int m = 0; m < RP; ++m) {
    ai[m] = a[i0 + m]; bi[m] = b[i0 + m];
    q[m] = 0.f;
  }

  const int jb = wv * SEGC;
  const float4* a4 = (const float4*)(a + jb)    + lane;
  const float4* b4 = (const float4*)(b + jb)    + lane;
  const float4* w4 = (const float4*)(w + jb)    + lane;
  const float4* c4 = (const float4*)(avga + jb) + lane;
  const float4* d4 = (const float4*)(avgb + jb) + lane;

#pragma unroll 1
  for (int k = 0; k < ITERS; ++k) {
    const int ix = k * 64;
    const float4 A = a4[ix], B = b4[ix], Wt = w4[ix], CA = c4[ix], CB = d4[ix];
#define P2E(e)                                                  \
    {                                                           \
      const float wrj = Wt.e * (CA.e - ha);                     \
      const float sj  = CB.e - hb;                              \
      _Pragma("unroll")                                         \
      for (int m = 0; m < RP; ++m) {                            \
        const float ta = ai[m] - A.e;                           \
        const float tb = bi[m] - B.e;                           \
        const float wdp = fmaf(Wt.e, fabsf(ta), -wrj);          \
        const float ep = fabsf(tb) - sj;                        \
        q[m] = fmaf(wdp, ep, q[m]);                             \
      }                                                         \
    }
    P2E(x) P2E(y) P2E(z) P2E(w)
#undef P2E
  }

#pragma unroll
  for (int off = 32; off >= 1; off >>= 1) {
#pragma unroll
    for (int m = 0; m < RP; ++m) q[m] += __shfl_xor(q[m], off);
  }

  __shared__ float lq[NW][RP];
  __shared__ double lab[RP];
  if (lane == 0) {
#pragma unroll
    for (int m = 0; m < RP; ++m) lq[wv][m] = q[m];
  }
  __syncthreads();
  if (threadIdx.x < RP) {                    // lanes 0-15 of wave 0 hold Wd etc.
    const int m = threadIdx.x;
    const double Qi = (double)lq[0][m] + lq[1][m] + lq[2][m] + lq[3][m];
    const double avA = (double)avga[i0 + m];
    const double avB = (double)avgb[i0 + m];
    const double ri = avA - had;
    const double si = avB - hbd;
    const double wi = (double)w[i0 + m];
    const double P0a = avA * (double)NN;
    const double P0b = avB * (double)NN;
    const double TAB = Qi - si * (P0a - Swrd) - ri * (P0b - Swsd) + ri * si * Wd;
    lab[m] = fabs(TAB) * wi;
  }
  __syncthreads();
  if (threadIdx.x == 0) {
    double s = 0.0;
#pragma unroll
    for (int m = 0; m < RP; ++m) s += lab[m];
    fAB[blockIdx.x] = s;
  }
}

// ---------- K3: finalize — reduce fAB + 9 moments; closed-form dens; power
__global__ __launch_bounds__(BLK) void k_fin(
    const double* __restrict__ fAB, const double* __restrict__ gmom,
    const int* __restrict__ powerPtr, float* __restrict__ out) {
  const int lane = threadIdx.x & 63;
  const int wv = threadIdx.x >> 6;

  double ab = 0.0;
#pragma unroll
  for (int k = 0; k < GBLK / BLK; ++k) ab += fAB[threadIdx.x + k * BLK];
  double p[NSC];
#pragma unroll
  for (int t = 0; t < NSC; ++t) {
    double s = 0.0;
#pragma unroll
    for (int k = 0; k < GBLK / BLK; ++k) s += gmom[t * GBLK + threadIdx.x + k * BLK];
    p[t] = s;
  }
#pragma unroll
  for (int off = 32; off >= 1; off >>= 1) {
    ab += __shfl_xor(ab, off);
#pragma unroll
    for (int t = 0; t < NSC; ++t) p[t] += __shfl_xor(p[t], off);
  }
  __shared__ double l[NW];
  __shared__ double lp[NSC][NW];
  if (lane == 0) {
    l[wv] = ab;
#pragma unroll
    for (int t = 0; t < NSC; ++t) lp[t][wv] = p[t];
  }
  __syncthreads();

  if (threadIdx.x == 0) {
    const double n2 = (double)NN * (double)NN;
    const double sab = l[0] + l[1] + l[2] + l[3];
    double sc[NSC];
#pragma unroll
    for (int t = 0; t < NSC; ++t) sc[t] = lp[t][0] + lp[t][1] + lp[t][2] + lp[t][3];
    const double W = sc[0], Ma1 = sc[1], Ma2 = sc[2], Mb1 = sc[3], Mb2 = sc[4];
    const double Sua1 = sc[5], Sua2 = sc[6], Sub1 = sc[7], Sub2 = sc[8];
    const double ha = Sua1 / (2.0 * NN);
    const double hb = Sub1 / (2.0 * NN);
    const double Swr  = Sua1 - ha * W;
    const double Sws  = Sub1 - hb * W;
    const double Swr2 = Sua2 - 2.0 * ha * Sua1 + ha * ha * W;
    const double Sws2 = Sub2 - 2.0 * hb * Sub1 + hb * hb * W;

    const double S_AA = 2.0 * W * Ma2 - 2.0 * Ma1 * Ma1
                      - 4.0 * (double)NN * (Swr2 + ha * Swr)
                      + 2.0 * W * Swr2 + 2.0 * Swr * Swr;
    const double S_BB = 2.0 * W * Mb2 - 2.0 * Mb1 * Mb1
                      - 4.0 * (double)NN * (Sws2 + hb * Sws)
                      + 2.0 * W * Sws2 + 2.0 * Sws * Sws;

    const double num = sab / n2;
    const double mAA = S_AA / n2;
    const double mBB = S_BB / n2;
    const double den = fabs(mAA * mBB);
    const int pw = powerPtr[0];
    double d;
    if (pw == 1) {
      d = num / sqrt(den + 1e-12);
    } else if (pw == 2) {
      d = (num * num) / (den + 1e-12);
    } else {
      d = pow(num / sqrt(mAA * mBB) + 1e-12, (double)pw);
    }
    if (isnan(d)) d = 0.0;
    if (d < 0.0) d = 0.0;
    out[0] = (float)d;
  }
}

// -------------------------------------------------------------------- launcher
extern "C" void kernel_launch(void* const* d_in, const int* in_sizes, int n_in,
                              void* d_out, int out_size, void* d_ws, size_t ws_size,
                              hipStream_t stream) {
  const float* a = (const float*)d_in[0];
  const float* b = (const float*)d_in[1];
  const float* w = (const float*)d_in[2];
  const int* power = (const int*)d_in[3];
  float* out = (float*)d_out;

  double* dws = (double*)d_ws;           // 8B-aligned base
  double* gmom = dws;                    // [9*512]
  double* fAB  = gmom + NSC * GBLK;      // [512]
  float* fp    = (float*)(fAB + GBLK);
  float* avga  = fp;                     // [N]
  float* avgb  = avga + NN;              // [N]

  k_pass1<<<GBLK, BLK, 0, stream>>>(a, b, w, avga, avgb, gmom);
  k_pass2<<<GBLK, BLK, 0, stream>>>(a, b, w, avga, avgb, gmom, fAB);
  k_fin<<<1, BLK, 0, stream>>>(fAB, gmom, power, out);
}

// Round 19
// 35.091 us; speedup vs baseline: 1.0344x; 1.0344x over previous
//
#include <hip/hip_runtime.h>
#include <math.h>

// DisCo (distance correlation) for N=8192, scalar output. THREE dispatches.
// R19 = exact revert to R17 (measured best, 35.3us). R18's pass1@RP16
// regressed (epilogue doubled + 2 accumulator banks; L2 saving smaller than
// pass2's) — pass1 optimum is RP=8, pass2 optimum is RP=16.
// Algebra (validated R11/R13/R15/R16, absmax 0.0):
//   ha = Sua1/(2N) (Sua1 = sum w_i avga_i); r_i = avga_i - ha
//   Q'_i = sum_j w_j (|a_i-a_j| - r_j)(|b_i-b_j| - s_j)   (5 VALU/pair)
//   T_AB_i = Q'_i - s_i(P0a_i-Swr) - r_i(P0b_i-Sws) + r_i s_i W
//   S_AA = 2W*Ma2 - 2Ma1^2 - 4N(Swr2 + ha*Swr) + 2W*Swr2 + 2Swr^2 (closed)
//   K1 k_pass1 (1024): 8 full rows/block; avg + 9 ha-free moment partials.
//   K2 k_pass2 (512):  16 full rows/block; prologue scalars; 5-op Q' sweep
//       with on-the-fly wr_j,s_j; in-block T_AB -> fAB[512].
//   K3 k_fin   (1x256): reduce fAB + moments; closed-form dens; power; clamp.
// No atomics/fences (R4). Fixed-order reductions -> deterministic.
// Ledger: R4 no per-block fences; R6 VGPR cliff; R9 epilogue<<main, 1-block
// reads <<100KB; R10 no redundant per-block O(N) rebuilds; R12 serial merge
// loses to gap; R14 packed-f32 neutral; R15/R17 ILP-for-TLP pays only when
// ops/byte rises AND epilogue stays small (R18: pass1@RP16 loses).

#define NN 8192
#define BLK 256
#define NW 4                      // waves per block
#define RP 8                      // pass1 rows per block
#define GBLK (NN / RP)            // 1024 pass1 blocks
#define RP2 16                    // pass2 rows per block
#define G2BLK (NN / RP2)          // 512 pass2 blocks
#define SEGC (NN / NW)            // 2048 cols per wave
#define ITERS (SEGC / 256)        // 8 float4-iters per wave
#define NSC 9   // 0:W 1:Ma1 2:Ma2 3:Mb1 4:Mb2 5:Sua1 6:Sua2 7:Sub1 8:Sub2

// ------------------------- K1: pass 1 — full rows, avg + ha-free moments
__global__ __launch_bounds__(BLK) void k_pass1(
    const float* __restrict__ a, const float* __restrict__ b,
    const float* __restrict__ w,
    float* __restrict__ avga, float* __restrict__ avgb,
    double* __restrict__ gmom) {
  const int lane = threadIdx.x & 63;
  const int wv = threadIdx.x >> 6;
  const int i0 = blockIdx.x * RP;

  float ai[RP], bi[RP], sa[RP], sb[RP];
#pragma unroll
  for (int m = 0; m < RP; ++m) {
    ai[m] = a[i0 + m]; bi[m] = b[i0 + m];
    sa[m] = 0.f; sb[m] = 0.f;
  }

  const int jb = wv * SEGC;
  const float4* a4 = (const float4*)(a + jb) + lane;
  const float4* b4 = (const float4*)(b + jb) + lane;
  const float4* w4 = (const float4*)(w + jb) + lane;

#pragma unroll 1
  for (int k = 0; k < ITERS; ++k) {
    const int ix = k * 64;
    const float4 A = a4[ix], B = b4[ix], Wt = w4[ix];
#define P1E(e)                                              \
    {                                                       \
      _Pragma("unroll")                                     \
      for (int m = 0; m < RP; ++m) {                        \
        sa[m] = fmaf(fabsf(ai[m] - A.e), Wt.e, sa[m]);      \
        sb[m] = fmaf(fabsf(bi[m] - B.e), Wt.e, sb[m]);      \
      }                                                     \
    }
    P1E(x) P1E(y) P1E(z) P1E(w)
#undef P1E
  }

#pragma unroll
  for (int off = 32; off >= 1; off >>= 1) {
#pragma unroll
    for (int m = 0; m < RP; ++m) {
      sa[m] += __shfl_xor(sa[m], off);
      sb[m] += __shfl_xor(sb[m], off);
    }
  }

  __shared__ float lsa[NW][RP], lsb[NW][RP];
  __shared__ double dmom[RP][NSC];
  if (lane == 0) {
#pragma unroll
    for (int m = 0; m < RP; ++m) { lsa[wv][m] = sa[m]; lsb[wv][m] = sb[m]; }
  }
  __syncthreads();
  if (threadIdx.x < RP) {
    const int m = threadIdx.x;
    const double rowA = (double)lsa[0][m] + lsa[1][m] + lsa[2][m] + lsa[3][m];
    const double rowB = (double)lsb[0][m] + lsb[1][m] + lsb[2][m] + lsb[3][m];
    const double avA = rowA * (1.0 / NN);
    const double avB = rowB * (1.0 / NN);
    avga[i0 + m] = (float)avA;
    avgb[i0 + m] = (float)avB;
    const double wi = (double)w[i0 + m];
    const double aiv = (double)a[i0 + m];
    const double biv = (double)b[i0 + m];
    dmom[m][0] = wi;
    dmom[m][1] = wi * aiv;
    dmom[m][2] = wi * aiv * aiv;
    dmom[m][3] = wi * biv;
    dmom[m][4] = wi * biv * biv;
    dmom[m][5] = wi * avA;
    dmom[m][6] = wi * avA * avA;
    dmom[m][7] = wi * avB;
    dmom[m][8] = wi * avB * avB;
  }
  __syncthreads();
  if (threadIdx.x == 0) {
#pragma unroll
    for (int t = 0; t < NSC; ++t) {
      double s = 0.0;
#pragma unroll
      for (int m = 0; m < RP; ++m) s += dmom[m][t];
      gmom[t * GBLK + blockIdx.x] = s;
    }
  }
}

// ---- K2: pass 2 — 16 full rows/block; prologue scalars; 5-op Q' sweep;
//      in-block T_AB finish -> fAB[512]
__global__ __launch_bounds__(BLK) void k_pass2(
    const float* __restrict__ a, const float* __restrict__ b,
    const float* __restrict__ w,
    const float* __restrict__ avga, const float* __restrict__ avgb,
    const double* __restrict__ gmom,
    double* __restrict__ fAB) {
  const int lane = threadIdx.x & 63;
  const int wv = threadIdx.x >> 6;
  const int i0 = blockIdx.x * RP2;

  // ---- prologue: W, Sua1, Sub1 -> ha, hb, Swr, Sws (all threads)
  double pW = 0.0, pU = 0.0, pV = 0.0;
#pragma unroll
  for (int k = 0; k < GBLK / BLK; ++k) {
    const int t = threadIdx.x + k * BLK;
    pW += gmom[0 * GBLK + t];
    pU += gmom[5 * GBLK + t];
    pV += gmom[7 * GBLK + t];
  }
#pragma unroll
  for (int off = 32; off >= 1; off >>= 1) {
    pW += __shfl_xor(pW, off);
    pU += __shfl_xor(pU, off);
    pV += __shfl_xor(pV, off);
  }
  __shared__ double l3[3][NW];
  if (lane == 0) { l3[0][wv] = pW; l3[1][wv] = pU; l3[2][wv] = pV; }
  __syncthreads();
  const double Wd   = l3[0][0] + l3[0][1] + l3[0][2] + l3[0][3];
  const double Sua1 = l3[1][0] + l3[1][1] + l3[1][2] + l3[1][3];
  const double Sub1 = l3[2][0] + l3[2][1] + l3[2][2] + l3[2][3];
  const double had = Sua1 / (2.0 * NN);
  const double hbd = Sub1 / (2.0 * NN);
  const double Swrd = Sua1 - had * Wd;
  const double Swsd = Sub1 - hbd * Wd;
  const float ha = (float)had, hb = (float)hbd;

  float ai[RP2], bi[RP2], q[RP2];
#pragma unroll
  for (int m = 0; m < RP2; ++m) {
    ai[m] = a[i0 + m]; bi[m] = b[i0 + m];
    q[m] = 0.f;
  }

  const int jb = wv * SEGC;
  const float4* a4 = (const float4*)(a + jb)    + lane;
  const float4* b4 = (const float4*)(b + jb)    + lane;
  const float4* w4 = (const float4*)(w + jb)    + lane;
  const float4* c4 = (const float4*)(avga + jb) + lane;
  const float4* d4 = (const float4*)(avgb + jb) + lane;

#pragma unroll 1
  for (int k = 0; k < ITERS; ++k) {
    const int ix = k * 64;
    const float4 A = a4[ix], B = b4[ix], Wt = w4[ix], CA = c4[ix], CB = d4[ix];
#define P2E(e)                                                  \
    {                                                           \
      const float wrj = Wt.e * (CA.e - ha);                     \
      const float sj  = CB.e - hb;                              \
      _Pragma("unroll")                                         \
      for (int m = 0; m < RP2; ++m) {                           \
        const float ta = ai[m] - A.e;                           \
        const float tb = bi[m] - B.e;                           \
        const float wdp = fmaf(Wt.e, fabsf(ta), -wrj);          \
        const float ep = fabsf(tb) - sj;                        \
        q[m] = fmaf(wdp, ep, q[m]);                             \
      }                                                         \
    }
    P2E(x) P2E(y) P2E(z) P2E(w)
#undef P2E
  }

#pragma unroll
  for (int off = 32; off >= 1; off >>= 1) {
#pragma unroll
    for (int m = 0; m < RP2; ++m) q[m] += __shfl_xor(q[m], off);
  }

  __shared__ float lq[NW][RP2];
  __shared__ double lab[RP2];
  if (lane == 0) {
#pragma unroll
    for (int m = 0; m < RP2; ++m) lq[wv][m] = q[m];
  }
  __syncthreads();
  if (threadIdx.x < RP2) {                    // lanes 0-15 of wave 0 hold Wd etc.
    const int m = threadIdx.x;
    const double Qi = (double)lq[0][m] + lq[1][m] + lq[2][m] + lq[3][m];
    const double avA = (double)avga[i0 + m];
    const double avB = (double)avgb[i0 + m];
    const double ri = avA - had;
    const double si = avB - hbd;
    const double wi = (double)w[i0 + m];
    const double P0a = avA * (double)NN;
    const double P0b = avB * (double)NN;
    const double TAB = Qi - si * (P0a - Swrd) - ri * (P0b - Swsd) + ri * si * Wd;
    lab[m] = fabs(TAB) * wi;
  }
  __syncthreads();
  if (threadIdx.x == 0) {
    double s = 0.0;
#pragma unroll
    for (int m = 0; m < RP2; ++m) s += lab[m];
    fAB[blockIdx.x] = s;
  }
}

// ---------- K3: finalize — reduce fAB + 9 moments; closed-form dens; power
__global__ __launch_bounds__(BLK) void k_fin(
    const double* __restrict__ fAB, const double* __restrict__ gmom,
    const int* __restrict__ powerPtr, float* __restrict__ out) {
  const int lane = threadIdx.x & 63;
  const int wv = threadIdx.x >> 6;

  double ab = 0.0;
#pragma unroll
  for (int k = 0; k < G2BLK / BLK; ++k) ab += fAB[threadIdx.x + k * BLK];
  double p[NSC];
#pragma unroll
  for (int t = 0; t < NSC; ++t) {
    double s = 0.0;
#pragma unroll
    for (int k = 0; k < GBLK / BLK; ++k) s += gmom[t * GBLK + threadIdx.x + k * BLK];
    p[t] = s;
  }
#pragma unroll
  for (int off = 32; off >= 1; off >>= 1) {
    ab += __shfl_xor(ab, off);
#pragma unroll
    for (int t = 0; t < NSC; ++t) p[t] += __shfl_xor(p[t], off);
  }
  __shared__ double l[NW];
  __shared__ double lp[NSC][NW];
  if (lane == 0) {
    l[wv] = ab;
#pragma unroll
    for (int t = 0; t < NSC; ++t) lp[t][wv] = p[t];
  }
  __syncthreads();

  if (threadIdx.x == 0) {
    const double n2 = (double)NN * (double)NN;
    const double sab = l[0] + l[1] + l[2] + l[3];
    double sc[NSC];
#pragma unroll
    for (int t = 0; t < NSC; ++t) sc[t] = lp[t][0] + lp[t][1] + lp[t][2] + lp[t][3];
    const double W = sc[0], Ma1 = sc[1], Ma2 = sc[2], Mb1 = sc[3], Mb2 = sc[4];
    const double Sua1 = sc[5], Sua2 = sc[6], Sub1 = sc[7], Sub2 = sc[8];
    const double ha = Sua1 / (2.0 * NN);
    const double hb = Sub1 / (2.0 * NN);
    const double Swr  = Sua1 - ha * W;
    const double Sws  = Sub1 - hb * W;
    const double Swr2 = Sua2 - 2.0 * ha * Sua1 + ha * ha * W;
    const double Sws2 = Sub2 - 2.0 * hb * Sub1 + hb * hb * W;

    const double S_AA = 2.0 * W * Ma2 - 2.0 * Ma1 * Ma1
                      - 4.0 * (double)NN * (Swr2 + ha * Swr)
                      + 2.0 * W * Swr2 + 2.0 * Swr * Swr;
    const double S_BB = 2.0 * W * Mb2 - 2.0 * Mb1 * Mb1
                      - 4.0 * (double)NN * (Sws2 + hb * Sws)
                      + 2.0 * W * Sws2 + 2.0 * Sws * Sws;

    const double num = sab / n2;
    const double mAA = S_AA / n2;
    const double mBB = S_BB / n2;
    const double den = fabs(mAA * mBB);
    const int pw = powerPtr[0];
    double d;
    if (pw == 1) {
      d = num / sqrt(den + 1e-12);
    } else if (pw == 2) {
      d = (num * num) / (den + 1e-12);
    } else {
      d = pow(num / sqrt(mAA * mBB) + 1e-12, (double)pw);
    }
    if (isnan(d)) d = 0.0;
    if (d < 0.0) d = 0.0;
    out[0] = (float)d;
  }
}

// -------------------------------------------------------------------- launcher
extern "C" void kernel_launch(void* const* d_in, const int* in_sizes, int n_in,
                              void* d_out, int out_size, void* d_ws, size_t ws_size,
                              hipStream_t stream) {
  const float* a = (const float*)d_in[0];
  const float* b = (const float*)d_in[1];
  const float* w = (const float*)d_in[2];
  const int* power = (const int*)d_in[3];
  float* out = (float*)d_out;

  double* dws = (double*)d_ws;           // 8B-aligned base
  double* gmom = dws;                    // [9*1024]
  double* fAB  = gmom + NSC * GBLK;      // [512]
  float* fp    = (float*)(fAB + G2BLK);
  float* avga  = fp;                     // [N]
  float* avgb  = avga + NN;              // [N]

  k_pass1<<<GBLK, BLK, 0, stream>>>(a, b, w, avga, avgb, gmom);
  k_pass2<<<G2BLK, BLK, 0, stream>>>(a, b, w, avga, avgb, gmom, fAB);
  k_fin<<<1, BLK, 0, stream>>>(fAB, gmom, power, out);
}